// Round 16
// baseline (133.324 us; speedup 1.0000x reference)
//
#include <hip/hip_runtime.h>
#include <hip/hip_bf16.h>

typedef __attribute__((ext_vector_type(4))) float f32x4;
typedef __attribute__((ext_vector_type(4))) unsigned int u32x4;
typedef __attribute__((ext_vector_type(8))) short s16x8;

#define B_  128
#define P_  196
#define E_  2048
#define D_  512
#define A_  512
#define M_  (B_*P_)   // 25088

// global_load_lds: 16B per lane, dest = wave-uniform base + lane*16
typedef __attribute__((address_space(1))) const unsigned int gu32;
typedef __attribute__((address_space(3))) unsigned int lu32;
__device__ __forceinline__ void gl_lds16(const void* g, void* l) {
  __builtin_amdgcn_global_load_lds((gu32*)g, (lu32*)l, 16, 0, 0);
}

#define WAIT_VM0() asm volatile("s_waitcnt vmcnt(0)" ::: "memory")
#define WAIT_LGKM0() asm volatile("s_waitcnt lgkmcnt(0)" ::: "memory")

// ---------------------------------------------------------------------------
// Kernel W: transpose + rne-bf16 + PRE-SWIZZLED 64K-tile store:
// WeTs[kt*32768 + ((a*64 + c8*8) ^ ((a&7)<<3)) + j] == exact 64KB LDS image
// of K-tile kt (a = n-row 0..511, kt = e>>6, c8 = (e&63)>>3, j = e&7).
// ---------------------------------------------------------------------------
__global__ void we_conv_kernel(const float* __restrict__ We,
                               unsigned short* __restrict__ WeTs) {
  __shared__ float tile[32][33];
  const int tx = threadIdx.x, ty = threadIdx.y;
  const int a0 = blockIdx.x * 32, e0 = blockIdx.y * 32;
  tile[ty][tx] = We[(e0 + ty) * A_ + a0 + tx];
  __syncthreads();
  const float v = tile[tx][ty];              // = We[e0+tx][a0+ty]
  const unsigned int u = __float_as_uint(v);
  const unsigned short r = (unsigned short)((u + 0x7fffu + ((u >> 16) & 1u)) >> 16);
  const int a = a0 + ty;                     // n-row 0..511
  const int kt = blockIdx.y >> 1;            // 64-wide e-tile
  const int c8 = ((blockIdx.y & 1) * 32 + tx) >> 3;   // 16B chunk within tile
  const int j = tx & 7;
  const int dest = ((a * 64 + c8 * 8) ^ ((a & 7) << 3)) + j;
  WeTs[kt * 32768 + dest] = r;
}

// ---------------------------------------------------------------------------
// Kernel A: att2pb[b][a] = decoder_hidden[b] @ Wd + bd[a] + be[a]  (fp32)
// ---------------------------------------------------------------------------
__global__ void att2_kernel(const float* __restrict__ h, const float* __restrict__ Wd,
                            const float* __restrict__ bd, const float* __restrict__ be,
                            float* __restrict__ att2pb) {
  const int b = blockIdx.x;
  const int t = threadIdx.x;  // 256
  __shared__ float hs[D_];
  hs[t] = h[b * D_ + t];
  hs[t + 256] = h[b * D_ + t + 256];
  __syncthreads();
  float a0 = 0.f, a1 = 0.f;
  for (int d = 0; d < D_; ++d) {
    const float hv = hs[d];
    a0 = fmaf(hv, Wd[d * A_ + t], a0);
    a1 = fmaf(hv, Wd[d * A_ + t + 256], a1);
  }
  att2pb[b * A_ + t] = a0 + bd[t] + be[t];
  att2pb[b * A_ + t + 256] = a1 + bd[t + 256] + be[t + 256];
}

// ---------------------------------------------------------------------------
__device__ inline unsigned pk2(float a, float b) {
  union { __hip_bfloat162 h; unsigned u; } cv;
  cv.h = __float22bfloat162_rn(make_float2(a, b));
  return cv.u;
}
__device__ inline u32x4 cvt8(const f32x4 lo, const f32x4 hi) {
  u32x4 r;
  r[0] = pk2(lo[0], lo[1]);
  r[1] = pk2(lo[2], lo[3]);
  r[2] = pk2(hi[0], hi[1]);
  r[3] = pk2(hi[2], hi[3]);
  return r;
}

// ---------------------------------------------------------------------------
// Kernel B v15: R10 structure at BK=64 — 32 K-iterations instead of 64, so
// the per-barrier residual (~1100 cyc) is paid half as often.  16 waves
// (1024 thr), wave tile 32x128 (4m x 4n), B ring-2 via gl_lds DMA
// (pre-swizzled 64KB images), A ring-2 via reg+cvt (load top / write bottom,
// full compute phase of cover), vmcnt(0)+lgkm(0)+barrier once per K-tile
// (all drained ops were issued a full ~5500-cyc compute phase earlier).
// LDS = 2x64KB (B) + 2x16KB (A) = 160 KiB exactly.
// ---------------------------------------------------------------------------
__launch_bounds__(1024, 4)
__global__ void score_kernel(const float* __restrict__ enc,
                             const unsigned short* __restrict__ WeTs,
                             const float* __restrict__ att2pb,
                             const float* __restrict__ Wf,
                             float* __restrict__ att_part) {
  __shared__ unsigned short Bh[2][512 * 64];   // 2 x 64 KB, swizzled image
  __shared__ unsigned short Ahs[2][128 * 64];  // 2 x 16 KB, swizzled image

  const int bid = blockIdx.x;               // 0..195
  const int m0 = bid * 128;

  const int t = threadIdx.x;                // 0..1023
  const int lane = t & 63, w = t >> 6;      // 16 waves
  const int wm = (w >> 2) * 32;             // 0 | 32 | 64 | 96
  const int wn = (w & 3) * 128;             // 0 | 128 | 256 | 384

  // A staging: row ar = t>>3 (0..127), 8 f32 at chunk ac8 = t&7 -> 16B write
  const int ar = t >> 3, ac8 = t & 7;
  const float* aptr = enc + (size_t)(m0 + ar) * E_ + ac8 * 8;
  const int awz = (ar * 64 + ac8 * 8) ^ ((ar & 7) << 3);

  // B DMA: 4 x 16B per thread (linear image copy); pass i at +i*8192 shorts
  const int doff = t * 8;

  // fragment read offsets: row*64 + ks*32 + q*8, XOR (fr&7)<<3
  const int q = lane >> 4, fr = lane & 15;
  const int fx = (fr & 7) << 3;
  int fa[2][2], fb[2][8];
#pragma unroll
  for (int ks = 0; ks < 2; ++ks) {
#pragma unroll
    for (int i = 0; i < 2; ++i)
      fa[ks][i] = ((wm + i * 16 + fr) * 64 + ks * 32 + q * 8) ^ fx;
#pragma unroll
    for (int j = 0; j < 8; ++j)
      fb[ks][j] = ((wn + j * 16 + fr) * 64 + ks * 32 + q * 8) ^ fx;
  }

  const f32x4 zero = {0.f, 0.f, 0.f, 0.f};
  f32x4 acc[2][8];
#pragma unroll
  for (int mi = 0; mi < 2; ++mi)
#pragma unroll
    for (int ni = 0; ni < 8; ++ni) acc[mi][ni] = zero;

  // ---- prologue: stage tile 0 (A regs -> cvt -> LDS; B DMA x4)
  {
    const f32x4 a0 = *(const f32x4*)(aptr);
    const f32x4 a1 = *(const f32x4*)(aptr + 4);
#pragma unroll
    for (int i = 0; i < 4; ++i)
      gl_lds16(WeTs + i * 8192 + doff, &Bh[0][i * 8192 + doff]);
    *(u32x4*)(&Ahs[0][awz]) = cvt8(a0, a1);
    WAIT_VM0();
    WAIT_LGKM0();
    __builtin_amdgcn_s_barrier();
  }

  for (int it = 0; it < 32; ++it) {
    const int cur = it & 1, nxt = cur ^ 1;
    f32x4 a0, a1;
    const bool stage = (it < 31);

    // 1) issue stage(t+1): 2 A-loads + 4 B-DMAs
    if (stage) {
      const int kof = (it + 1) * 64;
      a0 = *(const f32x4*)(aptr + kof);
      a1 = *(const f32x4*)(aptr + kof + 4);
      const unsigned short* sb = WeTs + (size_t)(it + 1) * 32768;
#pragma unroll
      for (int i = 0; i < 4; ++i)
        gl_lds16(sb + i * 8192 + doff, &Bh[nxt][i * 8192 + doff]);
    }

    // 2) compute tile t: two K=32 halves, B in halves of 4 (reg pressure)
    const unsigned short* AB = &Ahs[cur][0];
    const unsigned short* BB = &Bh[cur][0];
#pragma unroll
    for (int ks = 0; ks < 2; ++ks) {
      s16x8 fah[2], fbh[4];
      fah[0] = *(const s16x8*)(AB + fa[ks][0]);
      fah[1] = *(const s16x8*)(AB + fa[ks][1]);
#pragma unroll
      for (int j = 0; j < 4; ++j) fbh[j] = *(const s16x8*)(BB + fb[ks][j]);
      __builtin_amdgcn_s_setprio(1);
#pragma unroll
      for (int mi = 0; mi < 2; ++mi)
#pragma unroll
        for (int ni = 0; ni < 4; ++ni)
          acc[mi][ni] = __builtin_amdgcn_mfma_f32_16x16x32_bf16(fah[mi], fbh[ni], acc[mi][ni], 0, 0, 0);
      __builtin_amdgcn_s_setprio(0);
#pragma unroll
      for (int j = 0; j < 4; ++j) fbh[j] = *(const s16x8*)(BB + fb[ks][4 + j]);
      __builtin_amdgcn_s_setprio(1);
#pragma unroll
      for (int mi = 0; mi < 2; ++mi)
#pragma unroll
        for (int ni = 0; ni < 4; ++ni)
          acc[mi][4 + ni] = __builtin_amdgcn_mfma_f32_16x16x32_bf16(fah[mi], fbh[ni], acc[mi][4 + ni], 0, 0, 0);
      __builtin_amdgcn_s_setprio(0);
    }

    // 3) cvt + write A(t+1) (loads issued at top; full compute phase of cover)
    if (stage) {
      *(u32x4*)(&Ahs[nxt][awz]) = cvt8(a0, a1);
      // 4) drain: everything outstanding was issued at this iter's top
      WAIT_VM0();
      WAIT_LGKM0();
      __builtin_amdgcn_s_barrier();
    }
  }

  // epilogue: s = sum_col relu(acc + att2pb[b][col]) * Wf[col], 16-lane reduce
  // C/D layout: col = lane&15, row = (lane>>4)*4 + reg
  const int colL = wn + fr;
  float wfv[8];
#pragma unroll
  for (int ni = 0; ni < 8; ++ni) wfv[ni] = Wf[colL + ni * 16];
#pragma unroll
  for (int mi = 0; mi < 2; ++mi) {
    const int rowb = m0 + wm + mi * 16 + (q << 2);
#pragma unroll
    for (int r = 0; r < 4; ++r) {
      const int row = rowb + r;
      const int bb = row / P_;
      const float* a2 = att2pb + bb * A_ + colL;
      float s = 0.f;
#pragma unroll
      for (int ni = 0; ni < 8; ++ni)
        s += fmaxf(acc[mi][ni][r] + a2[ni * 16], 0.f) * wfv[ni];
#pragma unroll
      for (int off = 1; off < 16; off <<= 1) s += __shfl_xor(s, off);
      if (fr == 0) att_part[row * 4 + (w & 3)] = s;
    }
  }
}

// ---------------------------------------------------------------------------
// Kernel C: per (b, e-chunk): sum 4 partials -> softmax over P -> alpha,
// awe[b][e] = sum_p alpha[p] * enc[b][p][e].  grid = B*2, block 256.
// ---------------------------------------------------------------------------
__global__ void softmax_awe_kernel(const float* __restrict__ enc,
                                   const float* __restrict__ att_part,
                                   float* __restrict__ out) {
  const int bid = blockIdx.x;
  const int b = bid >> 1, ch = bid & 1;
  const int t = threadIdx.x;
  __shared__ float sm[256];
  __shared__ float alpha_s[P_];

  float av = -1e30f;
  if (t < P_) {
    const float* apt = att_part + (b * P_ + t) * 4;
    av = (apt[0] + apt[1]) + (apt[2] + apt[3]);
  }
  sm[t] = av;
  __syncthreads();
  for (int st = 128; st > 0; st >>= 1) {
    if (t < st) sm[t] = fmaxf(sm[t], sm[t + st]);
    __syncthreads();
  }
  const float mx = sm[0];
  __syncthreads();
  float ev = 0.f;
  if (t < P_) ev = __expf(av - mx);
  sm[t] = ev;
  __syncthreads();
  for (int st = 128; st > 0; st >>= 1) {
    if (t < st) sm[t] += sm[t + st];
    __syncthreads();
  }
  const float denom = sm[0];
  const float al = ev / denom;
  if (t < P_) {
    alpha_s[t] = al;
    if (ch == 0) out[B_ * E_ + b * P_ + t] = al;   // alpha output
  }
  __syncthreads();

  const int e0 = ch * 1024 + t * 4;
  const float* ebase = enc + (size_t)b * P_ * E_ + e0;
  f32x4 acc = {0.f, 0.f, 0.f, 0.f};
  for (int p = 0; p < P_; ++p) {
    const f32x4 v = *(const f32x4*)(ebase + (size_t)p * E_);
    const float a = alpha_s[p];
    acc.x += a * v.x; acc.y += a * v.y; acc.z += a * v.z; acc.w += a * v.w;
  }
  *(f32x4*)(out + b * E_ + e0) = acc;
}

// ---------------------------------------------------------------------------
extern "C" void kernel_launch(void* const* d_in, const int* in_sizes, int n_in,
                              void* d_out, int out_size, void* d_ws, size_t ws_size,
                              hipStream_t stream) {
  const float* enc = (const float*)d_in[0];
  const float* h   = (const float*)d_in[1];
  const float* We  = (const float*)d_in[2];
  const float* be  = (const float*)d_in[3];
  const float* Wd  = (const float*)d_in[4];
  const float* bd  = (const float*)d_in[5];
  const float* Wf  = (const float*)d_in[6];
  // d_in[7] = bf: constant shift before softmax -> cancels; unused.
  float* out = (float*)d_out;

  // workspace layout (~2.7 MB)
  float* att2pb = (float*)d_ws;                       // 128*512 f32
  float* att_part = att2pb + B_ * A_;                 // 25088*4 f32
  unsigned short* WeTs = (unsigned short*)(att_part + M_ * 4);  // 32*32768 u16

  we_conv_kernel<<<dim3(A_ / 32, E_ / 32), dim3(32, 32), 0, stream>>>(We, WeTs);
  att2_kernel<<<B_, 256, 0, stream>>>(h, Wd, bd, be, att2pb);
  score_kernel<<<M_ / 128, 1024, 0, stream>>>(enc, WeTs, att2pb, Wf, att_part);
  softmax_awe_kernel<<<B_ * 2, 256, 0, stream>>>(enc, att_part, out);
}

// Round 17
// 130.210 us; speedup vs baseline: 1.0239x; 1.0239x over previous
//
#include <hip/hip_runtime.h>
#include <hip/hip_bf16.h>

typedef __attribute__((ext_vector_type(2))) unsigned int u32x2;
typedef __attribute__((ext_vector_type(4))) float f32x4;
typedef __attribute__((ext_vector_type(4))) unsigned int u32x4;
typedef __attribute__((ext_vector_type(8))) short s16x8;

#define B_  128
#define P_  196
#define E_  2048
#define D_  512
#define A_  512
#define M_  (B_*P_)   // 25088
#define MT  112       // m-rows per block (224 blocks, all co-resident on 256 CUs)

// global_load_lds: 16B per lane, dest = wave-uniform base + lane*16
typedef __attribute__((address_space(1))) const unsigned int gu32;
typedef __attribute__((address_space(3))) unsigned int lu32;
__device__ __forceinline__ void gl_lds16(const void* g, void* l) {
  __builtin_amdgcn_global_load_lds((gu32*)g, (lu32*)l, 16, 0, 0);
}

#define WAIT_VM3() asm volatile("s_waitcnt vmcnt(3)" ::: "memory")
#define WAIT_VM0() asm volatile("s_waitcnt vmcnt(0)" ::: "memory")
#define WAIT_LGKM0() asm volatile("s_waitcnt lgkmcnt(0)" ::: "memory")

// ---------------------------------------------------------------------------
// Kernel W: transpose + rne-bf16 + PRE-SWIZZLED TILED store (R10 layout):
// WeTs[kt*16384 + ((a*32 + c8*8) ^ ((a&7)<<3)) + j] == exact 32KB LDS image
// of K-tile kt (a = n-row 0..511, c8 = (e&31)>>3, j = e&7).
// ---------------------------------------------------------------------------
__global__ void we_conv_kernel(const float* __restrict__ We,
                               unsigned short* __restrict__ WeTs) {
  __shared__ float tile[32][33];
  const int tx = threadIdx.x, ty = threadIdx.y;
  const int a0 = blockIdx.x * 32, e0 = blockIdx.y * 32;
  tile[ty][tx] = We[(e0 + ty) * A_ + a0 + tx];
  __syncthreads();
  const float v = tile[tx][ty];              // = We[e0+tx][a0+ty]
  const unsigned int u = __float_as_uint(v);
  const unsigned short r = (unsigned short)((u + 0x7fffu + ((u >> 16) & 1u)) >> 16);
  const int a = a0 + ty;                     // n-row 0..511
  const int kt = blockIdx.y;                 // e-tile
  const int c8 = tx >> 3, j = tx & 7;
  const int dest = ((a * 32 + c8 * 8) ^ ((a & 7) << 3)) + j;
  WeTs[kt * 16384 + dest] = r;
}

// ---------------------------------------------------------------------------
// Kernel A: att2pb[b][a] = decoder_hidden[b] @ Wd + bd[a] + be[a]  (fp32)
// ---------------------------------------------------------------------------
__global__ void att2_kernel(const float* __restrict__ h, const float* __restrict__ Wd,
                            const float* __restrict__ bd, const float* __restrict__ be,
                            float* __restrict__ att2pb) {
  const int b = blockIdx.x;
  const int t = threadIdx.x;  // 256
  __shared__ float hs[D_];
  hs[t] = h[b * D_ + t];
  hs[t + 256] = h[b * D_ + t + 256];
  __syncthreads();
  float a0 = 0.f, a1 = 0.f;
  for (int d = 0; d < D_; ++d) {
    const float hv = hs[d];
    a0 = fmaf(hv, Wd[d * A_ + t], a0);
    a1 = fmaf(hv, Wd[d * A_ + t + 256], a1);
  }
  att2pb[b * A_ + t] = a0 + bd[t] + be[t];
  att2pb[b * A_ + t + 256] = a1 + bd[t + 256] + be[t + 256];
}

// ---------------------------------------------------------------------------
__device__ inline unsigned pk2(float a, float b) {
  union { __hip_bfloat162 h; unsigned u; } cv;
  cv.h = __float22bfloat162_rn(make_float2(a, b));
  return cv.u;
}
__device__ __forceinline__ s16x8 ldsr(const unsigned short* p) {
  return *(const s16x8*)p;
}
#define MF(a, b, c) c = __builtin_amdgcn_mfma_f32_16x16x32_bf16(a, b, c, 0, 0, 0)

// ---------------------------------------------------------------------------
// Kernel B v16: R10 pipeline (16 waves, B ring-3 DMA + A ring-3 reg+cvt,
// depth-2 prefetch, counted vmcnt(3) + raw barrier) at 112-ROW M-TILES:
// grid = 224 blocks -> ALL 256 CUs' worth co-resident (R10's grid=196 left
// 60 CUs idle).  Wave tile = 112m x 32n (7 m-frags x 2 n-frags); A-frags
// shared by all 16 waves; per-wave LDS reads drop 10 -> 9 b128/iter.
// A staging rows 112-127 clamp-load row 111 (uniform 3 VMEM/iter, no OOB).
// ---------------------------------------------------------------------------
__launch_bounds__(1024, 4)
__global__ void score_kernel(const float* __restrict__ enc,
                             const unsigned short* __restrict__ WeTs,
                             const float* __restrict__ att2pb,
                             const float* __restrict__ Wf,
                             float* __restrict__ att_part) {
  __shared__ unsigned short Bh[3][512 * 32];   // 3 x 32 KB, swizzled image
  __shared__ unsigned short Ahs[3][128 * 32];  // 3 x  8 KB (rows 112-127 pad)

  const int bid = blockIdx.x;               // 0..223
  const int m0 = bid * MT;

  const int t = threadIdx.x;                // 0..1023
  const int lane = t & 63, w = t >> 6;      // 16 waves
  const int wn = w * 32;                    // wave n-origin: 0..480

  // A staging: row ar = t>>3 (0..127, clamped to 111), 4 f32 at chunk t&7
  const int ar = t >> 3, ac4 = t & 7;
  const int arc = ar < MT ? ar : MT - 1;    // clamp: uniform VMEM count, no OOB
  const float* aptr = enc + (size_t)(m0 + arc) * E_ + ac4 * 4;
  const int awz = (ar * 32 + ac4 * 4) ^ ((ar & 7) << 3);   // shorts, 8B-aligned

  // B DMA: 2 x 16B per thread (linear image copy)
  const int doff = t * 8;                   // shorts; chunk i at +i*8192

  // fragment read offsets
  const int q = lane >> 4, fr = lane & 15;
  const int fx = (fr & 7) << 3;
  int fa[7], fb[2];
#pragma unroll
  for (int i = 0; i < 7; ++i) fa[i] = ((i * 16 + fr) * 32 + q * 8) ^ fx;
#pragma unroll
  for (int j = 0; j < 2; ++j) fb[j] = ((wn + j * 16 + fr) * 32 + q * 8) ^ fx;

  const f32x4 zero = {0.f, 0.f, 0.f, 0.f};
  f32x4 acc[7][2];
#pragma unroll
  for (int mi = 0; mi < 7; ++mi) {
    acc[mi][0] = zero;
    acc[mi][1] = zero;
  }

  // rotating buffers: *_c = compute (tile t), *_1 = t+1, *_2 = DMA tgt (t+2)
  unsigned short *bAc = &Ahs[0][0], *bA1 = &Ahs[1][0], *bA2 = &Ahs[2][0];
  unsigned short *bBc = &Bh[0][0],  *bB1 = &Bh[1][0],  *bB2 = &Bh[2][0];

  f32x4 aC, aN;   // A regs: aC = tile t+1 (cvt at end of iter t), aN = t+2

  // ---- prologue: stage tiles 0 and 1 (order: A0, B0 x2, A1, B1 x2)
  {
    aC = *(const f32x4*)(aptr);                           // A(0)
    gl_lds16(WeTs + doff, bBc + doff);                    // B(0)
    gl_lds16(WeTs + 8192 + doff, bBc + 8192 + doff);
    aN = *(const f32x4*)(aptr + 32);                      // A(1)
    gl_lds16(WeTs + 16384 + doff, bB1 + doff);            // B(1)
    gl_lds16(WeTs + 16384 + 8192 + doff, bB1 + 8192 + doff);
    u32x2 av; av[0] = pk2(aC[0], aC[1]); av[1] = pk2(aC[2], aC[3]);
    *(u32x2*)(bAc + awz) = av;                            // A(0) -> LDS
    aC = aN;
    WAIT_VM3();     // retires B(0); leaves A(1)+B(1)x2 in flight
    WAIT_LGKM0();
    __builtin_amdgcn_s_barrier();
  }

  for (int it = 0; it < 62; ++it) {
    // 1) issue stage(t+2): 1 A-load + 2 B-DMAs  (3 VMEM ops this iter)
    const int kof = (it + 2) * 32;
    aN = *(const f32x4*)(aptr + kof);
    const unsigned short* sb = WeTs + (size_t)(it + 2) * 16384;
    gl_lds16(sb + doff, bB2 + doff);
    gl_lds16(sb + 8192 + doff, bB2 + 8192 + doff);

    // 2) compute buffer t: 2 B-frags held, stream 7 A-frags x 2 MFMA
    {
      s16x8 fbh0 = ldsr(bBc + fb[0]);
      s16x8 fbh1 = ldsr(bBc + fb[1]);
      __builtin_amdgcn_s_setprio(1);
#pragma unroll
      for (int mi = 0; mi < 7; ++mi) {
        const s16x8 fah = ldsr(bAc + fa[mi]);
        MF(fah, fbh0, acc[mi][0]);
        MF(fah, fbh1, acc[mi][1]);
      }
      __builtin_amdgcn_s_setprio(0);
    }

    // 3) cvt + write A(t+1) (aC regs issued last iter; compiler-counted wait)
    {
      u32x2 av; av[0] = pk2(aC[0], aC[1]); av[1] = pk2(aC[2], aC[3]);
      *(u32x2*)(bA1 + awz) = av;
    }
    aC = aN;

    // 4) counted drain: this iter's 3 stay in flight; tile t+1 fully resident
    WAIT_VM3();
    WAIT_LGKM0();
    __builtin_amdgcn_s_barrier();

    // 5) rotate
    unsigned short* tmp;
    tmp = bAc; bAc = bA1; bA1 = bA2; bA2 = tmp;
    tmp = bBc; bBc = bB1; bB1 = bB2; bB2 = tmp;
  }

  // ---- it = 62: compute tile 62, cvt+write A(63), full drain
  {
    s16x8 fbh0 = ldsr(bBc + fb[0]);
    s16x8 fbh1 = ldsr(bBc + fb[1]);
#pragma unroll
    for (int mi = 0; mi < 7; ++mi) {
      const s16x8 fah = ldsr(bAc + fa[mi]);
      MF(fah, fbh0, acc[mi][0]);
      MF(fah, fbh1, acc[mi][1]);
    }
    u32x2 av; av[0] = pk2(aC[0], aC[1]); av[1] = pk2(aC[2], aC[3]);
    *(u32x2*)(bA1 + awz) = av;                            // A(63)
    WAIT_VM0();     // B(63) retired
    WAIT_LGKM0();
    __builtin_amdgcn_s_barrier();
  }

  // ---- it = 63: compute tile 63 from bA1/bB1
  {
    s16x8 fbh0 = ldsr(bB1 + fb[0]);
    s16x8 fbh1 = ldsr(bB1 + fb[1]);
#pragma unroll
    for (int mi = 0; mi < 7; ++mi) {
      const s16x8 fah = ldsr(bA1 + fa[mi]);
      MF(fah, fbh0, acc[mi][0]);
      MF(fah, fbh1, acc[mi][1]);
    }
  }

  // epilogue: s = sum over this wave's 32 cols of relu(acc + att2)*Wf,
  // 16-lane reduce -> att_part[row][w] (16 slots per row).
  // C/D layout: col = lane&15, row = (lane>>4)*4 + reg
  const int colL = wn + fr;
  const float wf0 = Wf[colL], wf1 = Wf[colL + 16];
#pragma unroll
  for (int mi = 0; mi < 7; ++mi) {
    const int rowb = m0 + mi * 16 + (q << 2);
#pragma unroll
    for (int r = 0; r < 4; ++r) {
      const int row = rowb + r;
      const int bb = row / P_;
      const float* a2 = att2pb + bb * A_ + colL;
      float s = fmaxf(acc[mi][0][r] + a2[0], 0.f) * wf0
              + fmaxf(acc[mi][1][r] + a2[16], 0.f) * wf1;
#pragma unroll
      for (int off = 1; off < 16; off <<= 1) s += __shfl_xor(s, off);
      if (fr == 0) att_part[row * 16 + w] = s;
    }
  }
}

// ---------------------------------------------------------------------------
// Kernel C: per (b, e-chunk): sum 16 partials -> softmax over P -> alpha,
// awe[b][e] = sum_p alpha[p] * enc[b][p][e].  grid = B*2, block 256.
// ---------------------------------------------------------------------------
__global__ void softmax_awe_kernel(const float* __restrict__ enc,
                                   const float* __restrict__ att_part,
                                   float* __restrict__ out) {
  const int bid = blockIdx.x;
  const int b = bid >> 1, ch = bid & 1;
  const int t = threadIdx.x;
  __shared__ float sm[256];
  __shared__ float alpha_s[P_];

  float av = -1e30f;
  if (t < P_) {
    const float* apt = att_part + (b * P_ + t) * 16;
    float s = 0.f;
#pragma unroll
    for (int i = 0; i < 16; ++i) s += apt[i];
    av = s;
  }
  sm[t] = av;
  __syncthreads();
  for (int st = 128; st > 0; st >>= 1) {
    if (t < st) sm[t] = fmaxf(sm[t], sm[t + st]);
    __syncthreads();
  }
  const float mx = sm[0];
  __syncthreads();
  float ev = 0.f;
  if (t < P_) ev = __expf(av - mx);
  sm[t] = ev;
  __syncthreads();
  for (int st = 128; st > 0; st >>= 1) {
    if (t < st) sm[t] += sm[t + st];
    __syncthreads();
  }
  const float denom = sm[0];
  const float al = ev / denom;
  if (t < P_) {
    alpha_s[t] = al;
    if (ch == 0) out[B_ * E_ + b * P_ + t] = al;   // alpha output
  }
  __syncthreads();

  const int e0 = ch * 1024 + t * 4;
  const float* ebase = enc + (size_t)b * P_ * E_ + e0;
  f32x4 acc = {0.f, 0.f, 0.f, 0.f};
  for (int p = 0; p < P_; ++p) {
    const f32x4 v = *(const f32x4*)(ebase + (size_t)p * E_);
    const float a = alpha_s[p];
    acc.x += a * v.x; acc.y += a * v.y; acc.z += a * v.z; acc.w += a * v.w;
  }
  *(f32x4*)(out + b * E_ + e0) = acc;
}

// ---------------------------------------------------------------------------
extern "C" void kernel_launch(void* const* d_in, const int* in_sizes, int n_in,
                              void* d_out, int out_size, void* d_ws, size_t ws_size,
                              hipStream_t stream) {
  const float* enc = (const float*)d_in[0];
  const float* h   = (const float*)d_in[1];
  const float* We  = (const float*)d_in[2];
  const float* be  = (const float*)d_in[3];
  const float* Wd  = (const float*)d_in[4];
  const float* bd  = (const float*)d_in[5];
  const float* Wf  = (const float*)d_in[6];
  // d_in[7] = bf: constant shift before softmax -> cancels; unused.
  float* out = (float*)d_out;

  // workspace layout (~3.9 MB)
  float* att2pb = (float*)d_ws;                       // 128*512 f32
  float* att_part = att2pb + B_ * A_;                 // 25088*16 f32
  unsigned short* WeTs = (unsigned short*)(att_part + M_ * 16);  // 64*16384 u16

  we_conv_kernel<<<dim3(A_ / 32, E_ / 32), dim3(32, 32), 0, stream>>>(We, WeTs);
  att2_kernel<<<B_, 256, 0, stream>>>(h, Wd, bd, be, att2pb);
  score_kernel<<<M_ / MT, 1024, 0, stream>>>(enc, WeTs, att2pb, Wf, att_part);
  softmax_awe_kernel<<<B_ * 2, 256, 0, stream>>>(enc, att_part, out);
}

// Round 18
// 119.002 us; speedup vs baseline: 1.1203x; 1.0942x over previous
//
#include <hip/hip_runtime.h>
#include <hip/hip_bf16.h>

typedef __attribute__((ext_vector_type(2))) unsigned int u32x2;
typedef __attribute__((ext_vector_type(4))) float f32x4;
typedef __attribute__((ext_vector_type(8))) short s16x8;

#define B_  128
#define P_  196
#define E_  2048
#define D_  512
#define A_  512
#define M_  (B_*P_)   // 25088
#define MT  112       // m-rows per block -> 224 blocks

#define WAIT_LGKM0() asm volatile("s_waitcnt lgkmcnt(0)" ::: "memory")

// ---------------------------------------------------------------------------
// Kernel W: transpose + rne-bf16 + FRAGMENT-ORDER store:
// WeTf[kt*16384 + nf*512 + (q*16+fr)*8 + j] = bf16(We[kt*32+q*8+j][nf*16+fr])
// i.e. each 1KB record [kt][nf] is exactly the 64-lane B-fragment image:
// lane (q,fr) gets its 8 k-shorts contiguously -> wave load = coalesced 1KB.
// ---------------------------------------------------------------------------
__global__ void we_conv_kernel(const float* __restrict__ We,
                               unsigned short* __restrict__ WeTf) {
  __shared__ float tile[32][33];
  const int tx = threadIdx.x, ty = threadIdx.y;
  const int a0 = blockIdx.x * 32, e0 = blockIdx.y * 32;
  tile[ty][tx] = We[(e0 + ty) * A_ + a0 + tx];
  __syncthreads();
  const float v = tile[tx][ty];              // = We[e0+tx][a0+ty]
  const unsigned int u = __float_as_uint(v);
  const unsigned short r = (unsigned short)((u + 0x7fffu + ((u >> 16) & 1u)) >> 16);
  const int a = a0 + ty;                     // n-row 0..511
  const int kt = blockIdx.y;                 // K-tile (e = kt*32 + tx)
  const int q = tx >> 3, j = tx & 7;
  const int nf = a >> 4, fr = a & 15;
  WeTf[kt * 16384 + nf * 512 + (q * 16 + fr) * 8 + j] = r;
}

// ---------------------------------------------------------------------------
// Kernel A: att2pb[b][a] = decoder_hidden[b] @ Wd + bd[a] + be[a]  (fp32)
// ---------------------------------------------------------------------------
__global__ void att2_kernel(const float* __restrict__ h, const float* __restrict__ Wd,
                            const float* __restrict__ bd, const float* __restrict__ be,
                            float* __restrict__ att2pb) {
  const int b = blockIdx.x;
  const int t = threadIdx.x;  // 256
  __shared__ float hs[D_];
  hs[t] = h[b * D_ + t];
  hs[t + 256] = h[b * D_ + t + 256];
  __syncthreads();
  float a0 = 0.f, a1 = 0.f;
  for (int d = 0; d < D_; ++d) {
    const float hv = hs[d];
    a0 = fmaf(hv, Wd[d * A_ + t], a0);
    a1 = fmaf(hv, Wd[d * A_ + t + 256], a1);
  }
  att2pb[b * A_ + t] = a0 + bd[t] + be[t];
  att2pb[b * A_ + t + 256] = a1 + bd[t + 256] + be[t + 256];
}

// ---------------------------------------------------------------------------
__device__ inline unsigned pk2(float a, float b) {
  union { __hip_bfloat162 h; unsigned u; } cv;
  cv.h = __float22bfloat162_rn(make_float2(a, b));
  return cv.u;
}
__device__ __forceinline__ s16x8 ldsr(const unsigned short* p) {
  return *(const s16x8*)p;
}
#define MF(a, b, c) c = __builtin_amdgcn_mfma_f32_16x16x32_bf16(a, b, c, 0, 0, 0)

// ---------------------------------------------------------------------------
// Kernel B v17: B DIRECT FROM L2 in registers (fragment-order WeTf, coalesced
// 1KB wave loads, ping-pong bE/bO regs, depth-1 issue-after-use) — no B LDS,
// no vmcnt discipline (compiler-tracked register deps).  A stays in the
// R10/R16-proven LDS ring-3 (reg+cvt staging, depth-2), ONE barrier per
// K-tile guarding only the 8KB A tile.  16 waves, wave tile 112m x 32n
// (7 m-frags x 2 n-frags), 224 blocks.  LDS = 3 x 8 KB = 24 KB.
// ---------------------------------------------------------------------------
__launch_bounds__(1024, 4)
__global__ void score_kernel(const float* __restrict__ enc,
                             const unsigned short* __restrict__ WeTf,
                             const float* __restrict__ att2pb,
                             const float* __restrict__ Wf,
                             float* __restrict__ att_part) {
  __shared__ unsigned short Ahs[3][128 * 32];  // 3 x 8 KB ring (rows 112+ pad)

  const int bid = blockIdx.x;               // 0..223
  const int m0 = bid * MT;

  const int t = threadIdx.x;                // 0..1023
  const int lane = t & 63, w = t >> 6;      // 16 waves
  const int wn = w * 32;                    // wave n-origin

  // A staging: row ar = t>>3 (clamped to MT-1), 4 f32 at chunk t&7 -> 8B write
  const int ar = t >> 3, ac4 = t & 7;
  const int arc = ar < MT ? ar : MT - 1;
  const float* aptr = enc + (size_t)(m0 + arc) * E_ + ac4 * 4;
  const int awz = (ar * 32 + ac4 * 4) ^ ((ar & 7) << 3);

  // B direct: per-wave fragment-contiguous records.  frag (kt, j) at
  // bfp + kt*16384 + j*512   (nf = w*2 + j)
  const unsigned short* bfp = WeTf + (w * 2) * 512 + lane * 8;

  // A fragment read offsets
  const int q = lane >> 4, fr = lane & 15;
  const int fx = (fr & 7) << 3;
  int fa[7];
#pragma unroll
  for (int i = 0; i < 7; ++i) fa[i] = ((i * 16 + fr) * 32 + q * 8) ^ fx;

  const f32x4 zero = {0.f, 0.f, 0.f, 0.f};
  f32x4 acc[7][2];
#pragma unroll
  for (int mi = 0; mi < 7; ++mi) {
    acc[mi][0] = zero;
    acc[mi][1] = zero;
  }

  // A ring-3 rotating pointers
  unsigned short *bAc = &Ahs[0][0], *bA1 = &Ahs[1][0], *bA2 = &Ahs[2][0];
  f32x4 aC, aN;            // A(t+1) regs / A(t+2) in flight
  s16x8 bE0, bE1, bO0, bO1;  // B ping-pong: even tile / odd tile

  // ---- prologue: A(0)->LDS, aC=A(1), bE=B(0), bO=B(1)
  {
    aC = *(const f32x4*)(aptr);                    // A(0)
    bE0 = ldsr(bfp);                               // B(0)
    bE1 = ldsr(bfp + 512);
    aN = *(const f32x4*)(aptr + 32);               // A(1)
    bO0 = ldsr(bfp + 16384);                       // B(1)
    bO1 = ldsr(bfp + 16384 + 512);
    u32x2 av; av[0] = pk2(aC[0], aC[1]); av[1] = pk2(aC[2], aC[3]);
    *(u32x2*)(bAc + awz) = av;                     // A(0) -> LDS
    aC = aN;
    WAIT_LGKM0();
    __builtin_amdgcn_s_barrier();
  }

  // sub-iteration: compute tile TT from bAc x (BB0,BB1); then reload BB with
  // B(TT+2) (after last use), write A(TT+1), barrier, rotate A ring.
#define SUBITER(TT, BB0, BB1) {                                               \
    aN = *(const f32x4*)(aptr + ((TT) + 2) * 32);                             \
    __builtin_amdgcn_s_setprio(1);                                            \
    _Pragma("unroll")                                                         \
    for (int mi = 0; mi < 7; ++mi) {                                          \
      const s16x8 fah = ldsr(bAc + fa[mi]);                                   \
      MF(fah, BB0, acc[mi][0]);                                               \
      MF(fah, BB1, acc[mi][1]);                                               \
    }                                                                         \
    __builtin_amdgcn_s_setprio(0);                                            \
    BB0 = ldsr(bfp + ((TT) + 2) * 16384);                                     \
    BB1 = ldsr(bfp + ((TT) + 2) * 16384 + 512);                               \
    u32x2 av; av[0] = pk2(aC[0], aC[1]); av[1] = pk2(aC[2], aC[3]);           \
    *(u32x2*)(bA1 + awz) = av;                                                \
    aC = aN;                                                                  \
    WAIT_LGKM0();                                                             \
    __builtin_amdgcn_s_barrier();                                             \
    unsigned short* tmp_ = bAc; bAc = bA1; bA1 = bA2; bA2 = tmp_;             \
  }

  for (int it = 0; it < 62; it += 2) {
    SUBITER(it, bE0, bE1)
    SUBITER(it + 1, bO0, bO1)
  }
#undef SUBITER

  // ---- tile 62 (even, bE): no staging; write A(63); barrier; rotate
  {
    __builtin_amdgcn_s_setprio(1);
#pragma unroll
    for (int mi = 0; mi < 7; ++mi) {
      const s16x8 fah = ldsr(bAc + fa[mi]);
      MF(fah, bE0, acc[mi][0]);
      MF(fah, bE1, acc[mi][1]);
    }
    __builtin_amdgcn_s_setprio(0);
    u32x2 av; av[0] = pk2(aC[0], aC[1]); av[1] = pk2(aC[2], aC[3]);
    *(u32x2*)(bA1 + awz) = av;                     // A(63)
    WAIT_LGKM0();
    __builtin_amdgcn_s_barrier();
    unsigned short* tmp_ = bAc; bAc = bA1; bA1 = bA2; bA2 = tmp_;
  }

  // ---- tile 63 (odd, bO)
  {
#pragma unroll
    for (int mi = 0; mi < 7; ++mi) {
      const s16x8 fah = ldsr(bAc + fa[mi]);
      MF(fah, bO0, acc[mi][0]);
      MF(fah, bO1, acc[mi][1]);
    }
  }

  // epilogue: s = sum over this wave's 32 cols of relu(acc + att2)*Wf,
  // 16-lane reduce -> att_part[row][w].  C/D: col=lane&15, row=(lane>>4)*4+reg
  const int colL = wn + fr;
  const float wf0 = Wf[colL], wf1 = Wf[colL + 16];
#pragma unroll
  for (int mi = 0; mi < 7; ++mi) {
    const int rowb = m0 + mi * 16 + (q << 2);
#pragma unroll
    for (int r = 0; r < 4; ++r) {
      const int row = rowb + r;
      const int bb = row / P_;
      const float* a2 = att2pb + bb * A_ + colL;
      float s = fmaxf(acc[mi][0][r] + a2[0], 0.f) * wf0
              + fmaxf(acc[mi][1][r] + a2[16], 0.f) * wf1;
#pragma unroll
      for (int off = 1; off < 16; off <<= 1) s += __shfl_xor(s, off);
      if (fr == 0) att_part[row * 16 + w] = s;
    }
  }
}

// ---------------------------------------------------------------------------
// Kernel C: per (b, e-chunk): sum 16 partials -> softmax over P -> alpha,
// awe[b][e] = sum_p alpha[p] * enc[b][p][e].  grid = B*2, block 256.
// ---------------------------------------------------------------------------
__global__ void softmax_awe_kernel(const float* __restrict__ enc,
                                   const float* __restrict__ att_part,
                                   float* __restrict__ out) {
  const int bid = blockIdx.x;
  const int b = bid >> 1, ch = bid & 1;
  const int t = threadIdx.x;
  __shared__ float sm[256];
  __shared__ float alpha_s[P_];

  float av = -1e30f;
  if (t < P_) {
    const float* apt = att_part + (b * P_ + t) * 16;
    float s = 0.f;
#pragma unroll
    for (int i = 0; i < 16; ++i) s += apt[i];
    av = s;
  }
  sm[t] = av;
  __syncthreads();
  for (int st = 128; st > 0; st >>= 1) {
    if (t < st) sm[t] = fmaxf(sm[t], sm[t + st]);
    __syncthreads();
  }
  const float mx = sm[0];
  __syncthreads();
  float ev = 0.f;
  if (t < P_) ev = __expf(av - mx);
  sm[t] = ev;
  __syncthreads();
  for (int st = 128; st > 0; st >>= 1) {
    if (t < st) sm[t] += sm[t + st];
    __syncthreads();
  }
  const float denom = sm[0];
  const float al = ev / denom;
  if (t < P_) {
    alpha_s[t] = al;
    if (ch == 0) out[B_ * E_ + b * P_ + t] = al;   // alpha output
  }
  __syncthreads();

  const int e0 = ch * 1024 + t * 4;
  const float* ebase = enc + (size_t)b * P_ * E_ + e0;
  f32x4 acc = {0.f, 0.f, 0.f, 0.f};
  for (int p = 0; p < P_; ++p) {
    const f32x4 v = *(const f32x4*)(ebase + (size_t)p * E_);
    const float a = alpha_s[p];
    acc.x += a * v.x; acc.y += a * v.y; acc.z += a * v.z; acc.w += a * v.w;
  }
  *(f32x4*)(out + b * E_ + e0) = acc;
}

// ---------------------------------------------------------------------------
extern "C" void kernel_launch(void* const* d_in, const int* in_sizes, int n_in,
                              void* d_out, int out_size, void* d_ws, size_t ws_size,
                              hipStream_t stream) {
  const float* enc = (const float*)d_in[0];
  const float* h   = (const float*)d_in[1];
  const float* We  = (const float*)d_in[2];
  const float* be  = (const float*)d_in[3];
  const float* Wd  = (const float*)d_in[4];
  const float* bd  = (const float*)d_in[5];
  const float* Wf  = (const float*)d_in[6];
  // d_in[7] = bf: constant shift before softmax -> cancels; unused.
  float* out = (float*)d_out;

  // workspace layout (~3.9 MB)
  float* att2pb = (float*)d_ws;                       // 128*512 f32
  float* att_part = att2pb + B_ * A_;                 // 25088*16 f32
  unsigned short* WeTf = (unsigned short*)(att_part + M_ * 16);  // 64*16384 u16

  we_conv_kernel<<<dim3(A_ / 32, E_ / 32), dim3(32, 32), 0, stream>>>(We, WeTf);
  att2_kernel<<<B_, 256, 0, stream>>>(h, Wd, bd, be, att2pb);
  score_kernel<<<M_ / MT, 1024, 0, stream>>>(enc, WeTf, att2pb, Wf, att_part);
  softmax_awe_kernel<<<B_ * 2, 256, 0, stream>>>(enc, att_part, out);
}